// Round 10
// baseline (700.432 us; speedup 1.0000x reference)
//
#include <hip/hip_runtime.h>

// HeteroGNN forward (SAGE mean-aggr, two relations), MI355X.
//
// Round 10 = round 9 resubmitted (GPU acquisition timeout, no data):
//  - Persistent-grid partitioned count/scatter: grid = 2048 blocks (exactly
//    fills 256 CUs at 32 waves/CU with VGPR=8) so ALL blocks are co-resident
//    and the round-robin blockIdx&7 -> XCD mapping holds for the entire
//    kernel. Partition p's nbr slice (~2MB) should then stay dirty-resident
//    in XCD p's L2 -> writebacks collapse toward payload (~16MB). This is a
//    discriminating probe: if WRITE_SIZE stays ~250MB, L2 is no-write-
//    allocate for partial-line stores and scatter is at its floor.
//  - bf16-staged gather: xu/xr converted once to bf16 in ws; gather reads
//    ushort4 (8B/lane, 128B/row = 2 cache lines instead of 4). Gather is
//    line-count-bound on random L3 access -> ~40% faster. Output drift
//    ~0.01 << 0.13 threshold.
//  - scan, transform_v4 (named-VGPR W + readlane) unchanged.

// ---------------------------------------------------------------------------
// Phase A: persistent partitioned count.  p = blockIdx&7 (XCD), q = blockIdx>>3
// owns edge span [q*nE/nq, (q+1)*nE/nq).
// ---------------------------------------------------------------------------
__global__ void count_pers_kernel(const int* __restrict__ src, const int* __restrict__ dst,
                                  int* __restrict__ cnt, int Nr, int nE,
                                  float invR, float invU, int nq)
{
    const int p  = blockIdx.x & 7;
    const int q  = blockIdx.x >> 3;
    const int e0 = (int)((long long)q * nE / nq);
    const int e1 = (int)((long long)(q + 1) * nE / nq);
    for (int e = e0 + threadIdx.x; e < e1; e += blockDim.x) {
        const int dr = dst[e];
        const int su = src[e];
        if (min(7, (int)(dr * invR)) == p) atomicAdd(&cnt[dr], 1);
        if (min(7, (int)(su * invU)) == p) atomicAdd(&cnt[Nr + su], 1);
    }
}

#define SCAN_BS 2048   // elements per block in scan (256 thr x 8)

__global__ void scan_block_kernel(const int* __restrict__ cnt, int* __restrict__ off,
                                  int* __restrict__ partial, int N)
{
    __shared__ int sdata[256];
    const int t = threadIdx.x;
    const long long base = (long long)blockIdx.x * SCAN_BS + (long long)t * 8;
    int v[8];
    int s = 0;
    #pragma unroll
    for (int k = 0; k < 8; ++k) {
        long long i = base + k;
        v[k] = (i < N) ? cnt[i] : 0;
        s += v[k];
    }
    sdata[t] = s;
    __syncthreads();
    for (int d = 1; d < 256; d <<= 1) {
        int val = (t >= d) ? sdata[t - d] : 0;
        __syncthreads();
        if (t >= d) sdata[t] += val;
        __syncthreads();
    }
    if (t == 255) partial[blockIdx.x] = sdata[255];
    int run = sdata[t] - s;   // exclusive prefix for this thread's chunk
    #pragma unroll
    for (int k = 0; k < 8; ++k) {
        long long i = base + k;
        if (i < N) off[i] = run;
        run += v[k];
    }
}

__global__ void scan_partials_kernel(int* __restrict__ partial, int nb)
{
    __shared__ int sdata[256];
    const int t = threadIdx.x;
    int v = (t < nb) ? partial[t] : 0;
    sdata[t] = v;
    __syncthreads();
    for (int d = 1; d < 256; d <<= 1) {
        int val = (t >= d) ? sdata[t - d] : 0;
        __syncthreads();
        if (t >= d) sdata[t] += val;
        __syncthreads();
    }
    if (t < nb) partial[t] = sdata[t] - v;   // exclusive
}

__global__ void scan_addback_kernel(int* __restrict__ off, const int* __restrict__ partial,
                                    int N, int total)
{
    long long i = (long long)blockIdx.x * blockDim.x + threadIdx.x;
    if (i < N) off[i] += partial[i / SCAN_BS];
    if (i == 0) off[N] = total;
}

// ---------------------------------------------------------------------------
// Phase A2: persistent partitioned scatter (plain stores, slot via atomicSub
// on L2-resident cnt; all blocks co-resident -> partition pinned to one XCD).
// ---------------------------------------------------------------------------
__global__ void scatter_pers_kernel(const int* __restrict__ src, const int* __restrict__ dst,
                                    const int* __restrict__ off, int* __restrict__ cnt,
                                    int* __restrict__ nbr, int Nr, int nE,
                                    float invR, float invU, int nq)
{
    const int p  = blockIdx.x & 7;
    const int q  = blockIdx.x >> 3;
    const int e0 = (int)((long long)q * nE / nq);
    const int e1 = (int)((long long)(q + 1) * nE / nq);
    for (int e = e0 + threadIdx.x; e < e1; e += blockDim.x) {
        const int dr = dst[e];
        const int su = src[e];
        if (min(7, (int)(dr * invR)) == p) {
            int pos = off[dr] + atomicSub(&cnt[dr], 1) - 1;
            nbr[pos] = su;
        }
        if (min(7, (int)(su * invU)) == p) {
            int pos = off[Nr + su] + atomicSub(&cnt[Nr + su], 1) - 1;
            nbr[pos] = dr;
        }
    }
}

// ---------------------------------------------------------------------------
// bf16 conversion (RNE) of node features: float[n] -> ushort[n], vectorized.
// ---------------------------------------------------------------------------
__device__ __forceinline__ unsigned short f2bf(float f) {
    unsigned u = __float_as_uint(f);
    return (unsigned short)((u + 0x7FFF + ((u >> 16) & 1)) >> 16);
}

__global__ void tobf16_kernel(const float* __restrict__ x, unsigned short* __restrict__ y,
                              long long n4)
{
    long long i = (long long)blockIdx.x * blockDim.x + threadIdx.x;
    if (i >= n4) return;
    const float4 v = reinterpret_cast<const float4*>(x)[i];
    ushort4 o;
    o.x = f2bf(v.x); o.y = f2bf(v.y); o.z = f2bf(v.z); o.w = f2bf(v.w);
    reinterpret_cast<ushort4*>(y)[i] = o;
}

// ---------------------------------------------------------------------------
// Phase B: merged gather + mean, bf16 rows (128B/row, 2 lines). 16 lanes per
// node; lane loads ushort4 (8B = 4 feats). f32 accumulate, f32 row out.
// ---------------------------------------------------------------------------
__device__ __forceinline__ float bf2f(unsigned short h) {
    return __uint_as_float((unsigned)h << 16);
}

__device__ __forceinline__ void bfadd(float4& a, const ushort4 v) {
    a.x += bf2f(v.x); a.y += bf2f(v.y); a.z += bf2f(v.z); a.w += bf2f(v.w);
}

__global__ void gather_bf16_kernel(const unsigned short* __restrict__ xub,
                                   const unsigned short* __restrict__ xrb,
                                   const int* __restrict__ off,
                                   const int* __restrict__ nbr,
                                   float* __restrict__ out, int Nr, int NN)
{
    const int tid  = blockIdx.x * blockDim.x + threadIdx.x;
    const int g    = tid >> 4;
    if (g >= NN) return;
    const int lane = tid & 15;
    const int c    = lane << 2;
    const unsigned short* __restrict__ x = (g < Nr) ? xub : xrb;

    const int beg = off[g];
    const int end = off[g + 1];

    float4 a0 = {0,0,0,0}, a1 = {0,0,0,0}, a2 = {0,0,0,0}, a3 = {0,0,0,0};
    int j = beg;
    for (; j + 4 <= end; j += 4) {
        const int s0 = nbr[j], s1 = nbr[j+1], s2 = nbr[j+2], s3 = nbr[j+3];
        bfadd(a0, *reinterpret_cast<const ushort4*>(x + ((long long)s0 << 6) + c));
        bfadd(a1, *reinterpret_cast<const ushort4*>(x + ((long long)s1 << 6) + c));
        bfadd(a2, *reinterpret_cast<const ushort4*>(x + ((long long)s2 << 6) + c));
        bfadd(a3, *reinterpret_cast<const ushort4*>(x + ((long long)s3 << 6) + c));
    }
    for (; j < end; ++j) {
        bfadd(a0, *reinterpret_cast<const ushort4*>(x + ((long long)nbr[j] << 6) + c));
    }
    a0.x += a1.x + a2.x + a3.x;
    a0.y += a1.y + a2.y + a3.y;
    a0.z += a1.z + a2.z + a3.z;
    a0.w += a1.w + a2.w + a3.w;

    const float inv = 1.0f / (float)max(end - beg, 1);
    float4 r; r.x = a0.x * inv; r.y = a0.y * inv; r.z = a0.z * inv; r.w = a0.w * inv;
    *reinterpret_cast<float4*>(out + ((long long)g << 6) + c) = r;
}

// f32 gather fallback (if ws too small for bf16 staging)
__device__ __forceinline__ void f4add(float4& a, const float4 v) {
    a.x += v.x; a.y += v.y; a.z += v.z; a.w += v.w;
}

__global__ void gather_mean_all_kernel(const float* __restrict__ xu,
                                       const float* __restrict__ xr,
                                       const int* __restrict__ off,
                                       const int* __restrict__ nbr,
                                       float* __restrict__ out, int Nr, int NN)
{
    const int tid  = blockIdx.x * blockDim.x + threadIdx.x;
    const int g    = tid >> 4;
    if (g >= NN) return;
    const int lane = tid & 15;
    const int c    = lane << 2;
    const float* __restrict__ x = (g < Nr) ? xu : xr;

    const int beg = off[g];
    const int end = off[g + 1];

    float4 a0 = {0,0,0,0}, a1 = {0,0,0,0}, a2 = {0,0,0,0}, a3 = {0,0,0,0};
    int j = beg;
    for (; j + 4 <= end; j += 4) {
        const int s0 = nbr[j], s1 = nbr[j+1], s2 = nbr[j+2], s3 = nbr[j+3];
        f4add(a0, *reinterpret_cast<const float4*>(x + ((long long)s0 << 6) + c));
        f4add(a1, *reinterpret_cast<const float4*>(x + ((long long)s1 << 6) + c));
        f4add(a2, *reinterpret_cast<const float4*>(x + ((long long)s2 << 6) + c));
        f4add(a3, *reinterpret_cast<const float4*>(x + ((long long)s3 << 6) + c));
    }
    for (; j < end; ++j) {
        f4add(a0, *reinterpret_cast<const float4*>(x + ((long long)nbr[j] << 6) + c));
    }
    f4add(a0, a1); f4add(a2, a3); f4add(a0, a2);

    const float inv = 1.0f / (float)max(end - beg, 1);
    float4 r; r.x = a0.x * inv; r.y = a0.y * inv; r.z = a0.z * inv; r.w = a0.w * inv;
    *reinterpret_cast<float4*>(out + ((long long)g << 6) + c) = r;
}

// ---------------------------------------------------------------------------
// Phase C (v4): lane = output feature h and row element d; W in 128 named
// float4 VGPRs; readlane broadcasts row elements as SGPR operands to v_fmac.
// ---------------------------------------------------------------------------
__device__ __forceinline__ float rlane(float v, int l) {
    return __int_as_float(__builtin_amdgcn_readlane(__float_as_int(v), l));
}

#define LWV(nm, W, i) \
    float4 nm; nm.x = W[(4*(i)+0)*64 + lane]; nm.y = W[(4*(i)+1)*64 + lane]; \
    nm.z = W[(4*(i)+2)*64 + lane]; nm.w = W[(4*(i)+3)*64 + lane];

#define TSTEP(i, acc) { \
    acc = fmaf(rlane(va, 4*(i)+0), wl##i.x, acc); \
    acc = fmaf(rlane(va, 4*(i)+1), wl##i.y, acc); \
    acc = fmaf(rlane(va, 4*(i)+2), wl##i.z, acc); \
    acc = fmaf(rlane(va, 4*(i)+3), wl##i.w, acc); \
    acc = fmaf(rlane(vx, 4*(i)+0), wr##i.x, acc); \
    acc = fmaf(rlane(vx, 4*(i)+1), wr##i.y, acc); \
    acc = fmaf(rlane(vx, 4*(i)+2), wr##i.z, acc); \
    acc = fmaf(rlane(vx, 4*(i)+3), wr##i.w, acc); }

__global__ __launch_bounds__(256, 3)
void transform_v4_kernel(const float* __restrict__ agg,
                         const float* __restrict__ xroot,
                         const float* __restrict__ Wl,
                         const float* __restrict__ bl,
                         const float* __restrict__ Wr,
                         float* __restrict__ out, int N)
{
    const int lane = threadIdx.x & 63;
    const int wid  = (blockIdx.x * blockDim.x + threadIdx.x) >> 6;
    const int nw   = (gridDim.x * blockDim.x) >> 6;

    LWV(wl0,  Wl, 0)  LWV(wl1,  Wl, 1)  LWV(wl2,  Wl, 2)  LWV(wl3,  Wl, 3)
    LWV(wl4,  Wl, 4)  LWV(wl5,  Wl, 5)  LWV(wl6,  Wl, 6)  LWV(wl7,  Wl, 7)
    LWV(wl8,  Wl, 8)  LWV(wl9,  Wl, 9)  LWV(wl10, Wl, 10) LWV(wl11, Wl, 11)
    LWV(wl12, Wl, 12) LWV(wl13, Wl, 13) LWV(wl14, Wl, 14) LWV(wl15, Wl, 15)
    LWV(wr0,  Wr, 0)  LWV(wr1,  Wr, 1)  LWV(wr2,  Wr, 2)  LWV(wr3,  Wr, 3)
    LWV(wr4,  Wr, 4)  LWV(wr5,  Wr, 5)  LWV(wr6,  Wr, 6)  LWV(wr7,  Wr, 7)
    LWV(wr8,  Wr, 8)  LWV(wr9,  Wr, 9)  LWV(wr10, Wr, 10) LWV(wr11, Wr, 11)
    LWV(wr12, Wr, 12) LWV(wr13, Wr, 13) LWV(wr14, Wr, 14) LWV(wr15, Wr, 15)
    const float bias = bl[lane];

    for (int r = wid; r < N; r += nw) {
        const long long base = (long long)r << 6;
        const float va = agg[base + lane];     // coalesced; lane = element d
        const float vx = xroot[base + lane];
        float acc0 = bias, acc1 = 0.f, acc2 = 0.f, acc3 = 0.f;
        TSTEP(0,  acc0) TSTEP(1,  acc1) TSTEP(2,  acc2) TSTEP(3,  acc3)
        TSTEP(4,  acc0) TSTEP(5,  acc1) TSTEP(6,  acc2) TSTEP(7,  acc3)
        TSTEP(8,  acc0) TSTEP(9,  acc1) TSTEP(10, acc2) TSTEP(11, acc3)
        TSTEP(12, acc0) TSTEP(13, acc1) TSTEP(14, acc2) TSTEP(15, acc3)
        const float acc = (acc0 + acc1) + (acc2 + acc3);
        out[base + lane] = fmaxf(acc, 0.0f);   // lane = output feature h
    }
}

// ---------------------------------------------------------------------------
// Fallback (round-1) kernels, used only if ws_size is too small for CSR.
// ---------------------------------------------------------------------------
__global__ void edge_scatter_kernel(
    const float* __restrict__ xu, const float* __restrict__ xr,
    const int* __restrict__ src, const int* __restrict__ dst,
    float* __restrict__ agg_r, float* __restrict__ agg_u,
    float* __restrict__ deg_r, float* __restrict__ deg_u,
    int nE)
{
    int tid  = blockIdx.x * blockDim.x + threadIdx.x;
    int e    = tid >> 4;
    if (e >= nE) return;
    int lane = tid & 15;
    int su = src[e];
    int dr = dst[e];
    if (lane == 0) {
        atomicAdd(&deg_r[dr], 1.0f);
        atomicAdd(&deg_u[su], 1.0f);
    }
    const float4 a = *reinterpret_cast<const float4*>(xu + ((long long)su << 6) + (lane << 2));
    const float4 b = *reinterpret_cast<const float4*>(xr + ((long long)dr << 6) + (lane << 2));
    float* pr = agg_r + ((long long)dr << 6) + (lane << 2);
    float* pu = agg_u + ((long long)su << 6) + (lane << 2);
    atomicAdd(pr + 0, a.x); atomicAdd(pr + 1, a.y);
    atomicAdd(pr + 2, a.z); atomicAdd(pr + 3, a.w);
    atomicAdd(pu + 0, b.x); atomicAdd(pu + 1, b.y);
    atomicAdd(pu + 2, b.z); atomicAdd(pu + 3, b.w);
}

__global__ void transform_kernel(
    const float* __restrict__ agg, const float* __restrict__ deg,
    const float* __restrict__ xroot,
    const float* __restrict__ Wl, const float* __restrict__ bl,
    const float* __restrict__ Wr,
    float* __restrict__ out, int N)
{
    __shared__ float sWl[64 * 64];
    __shared__ float sWr[64 * 64];
    __shared__ float sb[64];
    __shared__ float sAgg[4][64];
    __shared__ float sX[4][64];

    const int t = threadIdx.x;
    for (int i = t; i < 64 * 64; i += 256) {
        sWl[i] = Wl[i];
        sWr[i] = Wr[i];
    }
    if (t < 64) sb[t] = bl[t];
    __syncthreads();

    const int rg = t >> 6;
    const int h  = t & 63;

    for (long long r0 = (long long)blockIdx.x * 4; r0 < N; r0 += (long long)gridDim.x * 4) {
        const long long r = r0 + rg;
        if (r < N) {
            float inv = 1.0f / fmaxf(deg[r], 1.0f);
            sAgg[rg][h] = agg[(r << 6) + h] * inv;
            sX[rg][h]   = xroot[(r << 6) + h];
        }
        __syncthreads();
        if (r < N) {
            float acc = sb[h];
            #pragma unroll
            for (int d = 0; d < 64; ++d) {
                acc += sAgg[rg][d] * sWl[d * 64 + h] + sX[rg][d] * sWr[d * 64 + h];
            }
            out[(r << 6) + h] = fmaxf(acc, 0.0f);
        }
        __syncthreads();
    }
}

extern "C" void kernel_launch(void* const* d_in, const int* in_sizes, int n_in,
                              void* d_out, int out_size, void* d_ws, size_t ws_size,
                              hipStream_t stream)
{
    const float* xu    = (const float*)d_in[0];
    const float* xr    = (const float*)d_in[1];
    const int*   src   = (const int*)  d_in[2];
    const int*   dst   = (const int*)  d_in[3];
    const float* Wl_ur = (const float*)d_in[4];
    const float* bl_ur = (const float*)d_in[5];
    const float* Wr_ur = (const float*)d_in[6];
    const float* Wl_ru = (const float*)d_in[7];
    const float* bl_ru = (const float*)d_in[8];
    const float* Wr_ru = (const float*)d_in[9];

    const int Nu = in_sizes[0] / 64;
    const int Nr = in_sizes[1] / 64;
    const int nE = in_sizes[2];
    const int NN = Nr + Nu;

    float* out   = (float*)d_out;
    float* agg_r = out;                        // [Nr,64]
    float* agg_u = out + (long long)Nr * 64;   // [Nu,64]

    // ---- workspace layout ----
    int* cnt     = (int*)d_ws;                  // [NN]
    int* off     = cnt + NN;                    // [NN+1]
    int* partial = off + NN + 1;                // [256]
    int* nbr     = partial + 256;               // [2E]
    // bf16 feature copies, 16B-aligned after nbr
    uintptr_t bfBase = ((uintptr_t)(nbr + 2ull * nE) + 15) & ~(uintptr_t)15;
    unsigned short* xub = (unsigned short*)bfBase;          // [Nu*64]
    unsigned short* xrb = xub + (size_t)Nu * 64;            // [Nr*64]
    const size_t needCsr = ((size_t)NN + NN + 1 + 256 + 2ull * nE) * sizeof(int);
    const size_t needBf  = (bfBase - (uintptr_t)d_ws) + (size_t)(Nu + Nr) * 64 * sizeof(unsigned short);

    if (ws_size >= needCsr) {
        // ---------------- CSR path ----------------
        hipMemsetAsync(cnt, 0, (size_t)NN * sizeof(int), stream);

        const bool useBf = (ws_size >= needBf);
        if (useBf) {
            const long long n4u = (long long)Nu * 16;
            const long long n4r = (long long)Nr * 16;
            tobf16_kernel<<<(int)((n4u + 255) / 256), 256, 0, stream>>>(xu, xub, n4u);
            tobf16_kernel<<<(int)((n4r + 255) / 256), 256, 0, stream>>>(xr, xrb, n4r);
        }

        const float invR = 8.0f / (float)Nr;
        const float invU = 8.0f / (float)Nu;
        const int PG = 2048;                 // persistent grid: 2048x256 = full machine
        const int nq = PG >> 3;

        count_pers_kernel<<<PG, 256, 0, stream>>>(src, dst, cnt, Nr, nE, invR, invU, nq);

        const int nScanBlocks = (NN + SCAN_BS - 1) / SCAN_BS;   // <= 256
        scan_block_kernel<<<nScanBlocks, 256, 0, stream>>>(cnt, off, partial, NN);
        scan_partials_kernel<<<1, 256, 0, stream>>>(partial, nScanBlocks);
        scan_addback_kernel<<<(NN + 255) / 256, 256, 0, stream>>>(off, partial, NN, 2 * nE);

        scatter_pers_kernel<<<PG, 256, 0, stream>>>(
            src, dst, off, cnt, nbr, Nr, nE, invR, invU, nq);

        // merged gather (mean fused; writes every output row)
        {
            const long long tg = (long long)NN * 16;
            const int gblocks = (int)((tg + 255) / 256);
            if (useBf) {
                gather_bf16_kernel<<<gblocks, 256, 0, stream>>>(
                    xub, xrb, off, nbr, out, Nr, NN);
            } else {
                gather_mean_all_kernel<<<gblocks, 256, 0, stream>>>(
                    xu, xr, off, nbr, out, Nr, NN);
            }
        }

        transform_v4_kernel<<<1024, 256, 0, stream>>>(
            agg_r, xr, Wl_ur, bl_ur, Wr_ur, agg_r, Nr);
        transform_v4_kernel<<<1024, 256, 0, stream>>>(
            agg_u, xu, Wl_ru, bl_ru, Wr_ru, agg_u, Nu);
    } else {
        // ---------------- fallback: atomic path ----------------
        float* deg_r = (float*)d_ws;
        float* deg_u = deg_r + Nr;
        hipMemsetAsync(d_out, 0, (size_t)out_size * sizeof(float), stream);
        hipMemsetAsync(d_ws, 0, (size_t)NN * sizeof(float), stream);

        const long long total = (long long)nE * 16;
        edge_scatter_kernel<<<(int)((total + 255) / 256), 256, 0, stream>>>(
            xu, xr, src, dst, agg_r, agg_u, deg_r, deg_u, nE);

        transform_kernel<<<2048, 256, 0, stream>>>(
            agg_r, deg_r, xr, Wl_ur, bl_ur, Wr_ur, agg_r, Nr);
        transform_kernel<<<2048, 256, 0, stream>>>(
            agg_u, deg_u, xu, Wl_ru, bl_ru, Wr_ru, agg_u, Nu);
    }
}

// Round 11
// 631.419 us; speedup vs baseline: 1.1093x; 1.1093x over previous
//
#include <hip/hip_runtime.h>

// HeteroGNN forward (SAGE mean-aggr, two relations), MI355X.
//
// Round 11:
//  - count: single-pass again (round-10 count_pers re-read edges 8x for no
//    measured benefit; WRITE amplification proved structural, not placement).
//  - scatter_pers kept: 172us @1.9TB/s is the floor (round-10 probe: full
//    co-residency did NOT reduce WRITE_SIZE -> L2 doesn't combine partial-
//    line stores; 4B random stores cost a 64B sector each, period).
//  - transform -> MFMA: gather emits bf16 agg into ws; W pre-transposed to
//    fragment layout Wt[col][k] bf16 (one tiny prep kernel); one wave per
//    16-row tile: 16x mfma_f32_16x16x32_bf16 (4 N-tiles x 2 K-steps x
//    {agg@Wl, x@Wr}), f32 acc + bias + relu, f32 out. Replaces the
//    VALU-bound readlane transform (512 cyc/row -> ~80 cyc/16 rows).
//    Layouts: A row=lane&15, k=(lane>>4)*8+j (contiguous 8, m97 pattern);
//    B col=lane&15 same k (via transposed W); C/D col=lane&15,
//    row=(lane>>4)*4+reg (m89-verified).
//  - Fallback tiers: no-MFMA ws -> bf16 gather to f32 + transform_v4;
//    no-bf16 ws -> f32 gather; tiny ws -> round-1 atomic path.

typedef __attribute__((ext_vector_type(8))) short bf16x8;   // 8 bf16 = 4 VGPR
typedef __attribute__((ext_vector_type(4))) float f32x4;    // 4 f32

// ---------------------------------------------------------------------------
// Phase A: single-pass count
// ---------------------------------------------------------------------------
__global__ void count_kernel(const int* __restrict__ src, const int* __restrict__ dst,
                             int* __restrict__ cnt, int Nr, int nE)
{
    int e = blockIdx.x * blockDim.x + threadIdx.x;
    if (e >= nE) return;
    atomicAdd(&cnt[dst[e]], 1);
    atomicAdd(&cnt[Nr + src[e]], 1);
}

#define SCAN_BS 2048   // elements per block in scan (256 thr x 8)

__global__ void scan_block_kernel(const int* __restrict__ cnt, int* __restrict__ off,
                                  int* __restrict__ partial, int N)
{
    __shared__ int sdata[256];
    const int t = threadIdx.x;
    const long long base = (long long)blockIdx.x * SCAN_BS + (long long)t * 8;
    int v[8];
    int s = 0;
    #pragma unroll
    for (int k = 0; k < 8; ++k) {
        long long i = base + k;
        v[k] = (i < N) ? cnt[i] : 0;
        s += v[k];
    }
    sdata[t] = s;
    __syncthreads();
    for (int d = 1; d < 256; d <<= 1) {
        int val = (t >= d) ? sdata[t - d] : 0;
        __syncthreads();
        if (t >= d) sdata[t] += val;
        __syncthreads();
    }
    if (t == 255) partial[blockIdx.x] = sdata[255];
    int run = sdata[t] - s;   // exclusive prefix for this thread's chunk
    #pragma unroll
    for (int k = 0; k < 8; ++k) {
        long long i = base + k;
        if (i < N) off[i] = run;
        run += v[k];
    }
}

__global__ void scan_partials_kernel(int* __restrict__ partial, int nb)
{
    __shared__ int sdata[256];
    const int t = threadIdx.x;
    int v = (t < nb) ? partial[t] : 0;
    sdata[t] = v;
    __syncthreads();
    for (int d = 1; d < 256; d <<= 1) {
        int val = (t >= d) ? sdata[t - d] : 0;
        __syncthreads();
        if (t >= d) sdata[t] += val;
        __syncthreads();
    }
    if (t < nb) partial[t] = sdata[t] - v;   // exclusive
}

__global__ void scan_addback_kernel(int* __restrict__ off, const int* __restrict__ partial,
                                    int N, int total)
{
    long long i = (long long)blockIdx.x * blockDim.x + threadIdx.x;
    if (i < N) off[i] += partial[i / SCAN_BS];
    if (i == 0) off[N] = total;
}

// ---------------------------------------------------------------------------
// Phase A2: persistent partitioned scatter (at its structural floor).
// ---------------------------------------------------------------------------
__global__ void scatter_pers_kernel(const int* __restrict__ src, const int* __restrict__ dst,
                                    const int* __restrict__ off, int* __restrict__ cnt,
                                    int* __restrict__ nbr, int Nr, int nE,
                                    float invR, float invU, int nq)
{
    const int p  = blockIdx.x & 7;
    const int q  = blockIdx.x >> 3;
    const int e0 = (int)((long long)q * nE / nq);
    const int e1 = (int)((long long)(q + 1) * nE / nq);
    for (int e = e0 + threadIdx.x; e < e1; e += blockDim.x) {
        const int dr = dst[e];
        const int su = src[e];
        if (min(7, (int)(dr * invR)) == p) {
            int pos = off[dr] + atomicSub(&cnt[dr], 1) - 1;
            nbr[pos] = su;
        }
        if (min(7, (int)(su * invU)) == p) {
            int pos = off[Nr + su] + atomicSub(&cnt[Nr + su], 1) - 1;
            nbr[pos] = dr;
        }
    }
}

// ---------------------------------------------------------------------------
// bf16 helpers
// ---------------------------------------------------------------------------
__device__ __forceinline__ unsigned short f2bf(float f) {
    unsigned u = __float_as_uint(f);
    return (unsigned short)((u + 0x7FFF + ((u >> 16) & 1)) >> 16);
}
__device__ __forceinline__ float bf2f(unsigned short h) {
    return __uint_as_float((unsigned)h << 16);
}

__global__ void tobf16_kernel(const float* __restrict__ x, unsigned short* __restrict__ y,
                              long long n4)
{
    long long i = (long long)blockIdx.x * blockDim.x + threadIdx.x;
    if (i >= n4) return;
    const float4 v = reinterpret_cast<const float4*>(x)[i];
    ushort4 o;
    o.x = f2bf(v.x); o.y = f2bf(v.y); o.z = f2bf(v.z); o.w = f2bf(v.w);
    reinterpret_cast<ushort4*>(y)[i] = o;
}

// W prep: 4 f32 [k=64][col=64] matrices -> bf16 transposed [mat][col][k].
__global__ void wprep_kernel(const float* __restrict__ W0, const float* __restrict__ W1,
                             const float* __restrict__ W2, const float* __restrict__ W3,
                             unsigned short* __restrict__ Wt)
{
    int i = blockIdx.x * blockDim.x + threadIdx.x;   // 4*4096
    if (i >= 4 * 4096) return;
    const int mat = i >> 12, r = i & 4095, col = r >> 6, k = r & 63;
    const float* W = (mat == 0) ? W0 : (mat == 1) ? W1 : (mat == 2) ? W2 : W3;
    Wt[i] = f2bf(W[k * 64 + col]);
}

// ---------------------------------------------------------------------------
// Phase B: merged gather + mean from bf16 features. Two output flavors.
// ---------------------------------------------------------------------------
__device__ __forceinline__ void bfadd(float4& a, const ushort4 v) {
    a.x += bf2f(v.x); a.y += bf2f(v.y); a.z += bf2f(v.z); a.w += bf2f(v.w);
}

template <bool BF_OUT>
__device__ __forceinline__ void gather_body(const unsigned short* __restrict__ xub,
                                            const unsigned short* __restrict__ xrb,
                                            const int* __restrict__ off,
                                            const int* __restrict__ nbr,
                                            float* fout, unsigned short* bout,
                                            int Nr, int NN)
{
    const int tid  = blockIdx.x * blockDim.x + threadIdx.x;
    const int g    = tid >> 4;
    if (g >= NN) return;
    const int lane = tid & 15;
    const int c    = lane << 2;
    const unsigned short* __restrict__ x = (g < Nr) ? xub : xrb;

    const int beg = off[g];
    const int end = off[g + 1];

    float4 a0 = {0,0,0,0}, a1 = {0,0,0,0}, a2 = {0,0,0,0}, a3 = {0,0,0,0};
    int j = beg;
    for (; j + 4 <= end; j += 4) {
        const int s0 = nbr[j], s1 = nbr[j+1], s2 = nbr[j+2], s3 = nbr[j+3];
        bfadd(a0, *reinterpret_cast<const ushort4*>(x + ((long long)s0 << 6) + c));
        bfadd(a1, *reinterpret_cast<const ushort4*>(x + ((long long)s1 << 6) + c));
        bfadd(a2, *reinterpret_cast<const ushort4*>(x + ((long long)s2 << 6) + c));
        bfadd(a3, *reinterpret_cast<const ushort4*>(x + ((long long)s3 << 6) + c));
    }
    for (; j < end; ++j) {
        bfadd(a0, *reinterpret_cast<const ushort4*>(x + ((long long)nbr[j] << 6) + c));
    }
    a0.x += a1.x + a2.x + a3.x;
    a0.y += a1.y + a2.y + a3.y;
    a0.z += a1.z + a2.z + a3.z;
    a0.w += a1.w + a2.w + a3.w;

    const float inv = 1.0f / (float)max(end - beg, 1);
    if (BF_OUT) {
        ushort4 o;
        o.x = f2bf(a0.x * inv); o.y = f2bf(a0.y * inv);
        o.z = f2bf(a0.z * inv); o.w = f2bf(a0.w * inv);
        *reinterpret_cast<ushort4*>(bout + ((long long)g << 6) + c) = o;
    } else {
        float4 r; r.x = a0.x * inv; r.y = a0.y * inv; r.z = a0.z * inv; r.w = a0.w * inv;
        *reinterpret_cast<float4*>(fout + ((long long)g << 6) + c) = r;
    }
}

__global__ void gather_bf16b_kernel(const unsigned short* __restrict__ xub,
                                    const unsigned short* __restrict__ xrb,
                                    const int* __restrict__ off, const int* __restrict__ nbr,
                                    unsigned short* __restrict__ aggb, int Nr, int NN)
{ gather_body<true>(xub, xrb, off, nbr, nullptr, aggb, Nr, NN); }

__global__ void gather_bf16_kernel(const unsigned short* __restrict__ xub,
                                   const unsigned short* __restrict__ xrb,
                                   const int* __restrict__ off, const int* __restrict__ nbr,
                                   float* __restrict__ out, int Nr, int NN)
{ gather_body<false>(xub, xrb, off, nbr, out, nullptr, Nr, NN); }

// f32 gather fallback (no bf16 staging room)
__device__ __forceinline__ void f4add(float4& a, const float4 v) {
    a.x += v.x; a.y += v.y; a.z += v.z; a.w += v.w;
}

__global__ void gather_mean_all_kernel(const float* __restrict__ xu,
                                       const float* __restrict__ xr,
                                       const int* __restrict__ off,
                                       const int* __restrict__ nbr,
                                       float* __restrict__ out, int Nr, int NN)
{
    const int tid  = blockIdx.x * blockDim.x + threadIdx.x;
    const int g    = tid >> 4;
    if (g >= NN) return;
    const int lane = tid & 15;
    const int c    = lane << 2;
    const float* __restrict__ x = (g < Nr) ? xu : xr;
    const int beg = off[g];
    const int end = off[g + 1];
    float4 a0 = {0,0,0,0}, a1 = {0,0,0,0}, a2 = {0,0,0,0}, a3 = {0,0,0,0};
    int j = beg;
    for (; j + 4 <= end; j += 4) {
        const int s0 = nbr[j], s1 = nbr[j+1], s2 = nbr[j+2], s3 = nbr[j+3];
        f4add(a0, *reinterpret_cast<const float4*>(x + ((long long)s0 << 6) + c));
        f4add(a1, *reinterpret_cast<const float4*>(x + ((long long)s1 << 6) + c));
        f4add(a2, *reinterpret_cast<const float4*>(x + ((long long)s2 << 6) + c));
        f4add(a3, *reinterpret_cast<const float4*>(x + ((long long)s3 << 6) + c));
    }
    for (; j < end; ++j)
        f4add(a0, *reinterpret_cast<const float4*>(x + ((long long)nbr[j] << 6) + c));
    f4add(a0, a1); f4add(a2, a3); f4add(a0, a2);
    const float inv = 1.0f / (float)max(end - beg, 1);
    float4 r; r.x = a0.x * inv; r.y = a0.y * inv; r.z = a0.z * inv; r.w = a0.w * inv;
    *reinterpret_cast<float4*>(out + ((long long)g << 6) + c) = r;
}

// ---------------------------------------------------------------------------
// Phase C (MFMA): out[16-row tile] = relu(agg_bf @ Wl + bias + x_bf @ Wr).
// One wave per tile. Wlt/Wrt are bf16 [col][k] (fragment-friendly).
// ---------------------------------------------------------------------------
#define WFRAG(P, n, ks) (*reinterpret_cast<const bf16x8*>((P) + ((n)*16 + l15)*64 + (ks)*32 + l4*8))

__global__ __launch_bounds__(256, 2)
void transform_mfma_kernel(const unsigned short* __restrict__ aggb,
                           const unsigned short* __restrict__ xb,
                           const unsigned short* __restrict__ Wlt,
                           const unsigned short* __restrict__ Wrt,
                           const float* __restrict__ bl,
                           float* __restrict__ out, int N)
{
    const int lane = threadIdx.x & 63;
    const int l15  = lane & 15;
    const int l4   = lane >> 4;
    const int wid  = (blockIdx.x * blockDim.x + threadIdx.x) >> 6;
    const int nTiles = (N + 15) >> 4;
    if (wid >= nTiles) return;

    // W fragments: 16 x bf16x8 (64 VGPR), loaded once per wave.
    const bf16x8 wl00 = WFRAG(Wlt, 0, 0), wl01 = WFRAG(Wlt, 0, 1);
    const bf16x8 wl10 = WFRAG(Wlt, 1, 0), wl11 = WFRAG(Wlt, 1, 1);
    const bf16x8 wl20 = WFRAG(Wlt, 2, 0), wl21 = WFRAG(Wlt, 2, 1);
    const bf16x8 wl30 = WFRAG(Wlt, 3, 0), wl31 = WFRAG(Wlt, 3, 1);
    const bf16x8 wr00 = WFRAG(Wrt, 0, 0), wr01 = WFRAG(Wrt, 0, 1);
    const bf16x8 wr10 = WFRAG(Wrt, 1, 0), wr11 = WFRAG(Wrt, 1, 1);
    const bf16x8 wr20 = WFRAG(Wrt, 2, 0), wr21 = WFRAG(Wrt, 2, 1);
    const bf16x8 wr30 = WFRAG(Wrt, 3, 0), wr31 = WFRAG(Wrt, 3, 1);

    const float b0 = bl[l15], b1 = bl[16 + l15], b2 = bl[32 + l15], b3 = bl[48 + l15];

    const int tb = wid << 4;
    const int arow = min(tb + l15, N - 1);         // clamp (N%16==0 normally)
    const unsigned short* pa = aggb + (long long)arow * 64;
    const unsigned short* px = xb   + (long long)arow * 64;

    const bf16x8 a0 = *reinterpret_cast<const bf16x8*>(pa + l4 * 8);
    const bf16x8 a1 = *reinterpret_cast<const bf16x8*>(pa + 32 + l4 * 8);
    const bf16x8 x0 = *reinterpret_cast<const bf16x8*>(px + l4 * 8);
    const bf16x8 x1 = *reinterpret_cast<const bf16x8*>(px + 32 + l4 * 8);

    f32x4 acc0 = {b0, b0, b0, b0};
    f32x4 acc1 = {b1, b1, b1, b1};
    f32x4 acc2 = {b2, b2, b2, b2};
    f32x4 acc3 = {b3, b3, b3, b3};

    acc0 = __builtin_amdgcn_mfma_f32_16x16x32_bf16(a0, wl00, acc0, 0, 0, 0);
    acc0 = __builtin_amdgcn_mfma_f32_16x16x32_bf16(a1, wl01, acc0, 0, 0, 0);
    acc0 = __builtin_amdgcn_mfma_f32_16x16x32_bf16(x0, wr00, acc0, 0, 0, 0);
    acc0 = __builtin_amdgcn_mfma_f32_16x16x32_bf16(x1, wr01, acc0, 0, 0, 0);

    acc1 = __builtin_amdgcn_mfma_f32_16x16x32_bf16(a0, wl10, acc1, 0, 0, 0);
    acc1 = __builtin_amdgcn_mfma_f32_16x16x32_bf16(a1, wl11, acc1, 0, 0, 0);
    acc1 = __builtin_amdgcn_mfma_f32_16x16x32_bf16(x0, wr10, acc1, 0, 0, 0);
    acc1 = __builtin_amdgcn_mfma_f32_16x16x32_bf16(x1, wr11, acc1, 0, 0, 0);

    acc2 = __builtin_amdgcn_mfma_f32_16x16x32_bf16(a0, wl20, acc2, 0, 0, 0);
    acc2 = __builtin_amdgcn_mfma_f32_16x16x32_bf16(a1, wl21, acc2, 0, 0, 0);
    acc2 = __builtin_amdgcn_mfma_f32_16x16x32_bf16(x0, wr20, acc2, 0, 0, 0);
    acc2 = __builtin_amdgcn_mfma_f32_16x16x32_bf16(x1, wr21, acc2, 0, 0, 0);

    acc3 = __builtin_amdgcn_mfma_f32_16x16x32_bf16(a0, wl30, acc3, 0, 0, 0);
    acc3 = __builtin_amdgcn_mfma_f32_16x16x32_bf16(a1, wl31, acc3, 0, 0, 0);
    acc3 = __builtin_amdgcn_mfma_f32_16x16x32_bf16(x0, wr30, acc3, 0, 0, 0);
    acc3 = __builtin_amdgcn_mfma_f32_16x16x32_bf16(x1, wr31, acc3, 0, 0, 0);

    // store: row = tb + l4*4 + r, col = n*16 + l15
    float* po = out + (long long)tb * 64;
    #pragma unroll
    for (int r = 0; r < 4; ++r) {
        const int row = tb + l4 * 4 + r;
        if (row < N) {
            float* prow = po + (long long)(l4 * 4 + r) * 64 + l15;
            prow[0]  = fmaxf(acc0[r], 0.0f);
            prow[16] = fmaxf(acc1[r], 0.0f);
            prow[32] = fmaxf(acc2[r], 0.0f);
            prow[48] = fmaxf(acc3[r], 0.0f);
        }
    }
}

// ---------------------------------------------------------------------------
// Phase C fallback (v4): readlane transform (round 6), reads f32 agg/x.
// ---------------------------------------------------------------------------
__device__ __forceinline__ float rlane(float v, int l) {
    return __int_as_float(__builtin_amdgcn_readlane(__float_as_int(v), l));
}

#define LWV(nm, W, i) \
    float4 nm; nm.x = W[(4*(i)+0)*64 + lane]; nm.y = W[(4*(i)+1)*64 + lane]; \
    nm.z = W[(4*(i)+2)*64 + lane]; nm.w = W[(4*(i)+3)*64 + lane];

#define TSTEP(i, acc) { \
    acc = fmaf(rlane(va, 4*(i)+0), wl##i.x, acc); \
    acc = fmaf(rlane(va, 4*(i)+1), wl##i.y, acc); \
    acc = fmaf(rlane(va, 4*(i)+2), wl##i.z, acc); \
    acc = fmaf(rlane(va, 4*(i)+3), wl##i.w, acc); \
    acc = fmaf(rlane(vx, 4*(i)+0), wr##i.x, acc); \
    acc = fmaf(rlane(vx, 4*(i)+1), wr##i.y, acc); \
    acc = fmaf(rlane(vx, 4*(i)+2), wr##i.z, acc); \
    acc = fmaf(rlane(vx, 4*(i)+3), wr##i.w, acc); }

__global__ __launch_bounds__(256, 3)
void transform_v4_kernel(const float* __restrict__ agg,
                         const float* __restrict__ xroot,
                         const float* __restrict__ Wl,
                         const float* __restrict__ bl,
                         const float* __restrict__ Wr,
                         float* __restrict__ out, int N)
{
    const int lane = threadIdx.x & 63;
    const int wid  = (blockIdx.x * blockDim.x + threadIdx.x) >> 6;
    const int nw   = (gridDim.x * blockDim.x) >> 6;

    LWV(wl0,  Wl, 0)  LWV(wl1,  Wl, 1)  LWV(wl2,  Wl, 2)  LWV(wl3,  Wl, 3)
    LWV(wl4,  Wl, 4)  LWV(wl5,  Wl, 5)  LWV(wl6,  Wl, 6)  LWV(wl7,  Wl, 7)
    LWV(wl8,  Wl, 8)  LWV(wl9,  Wl, 9)  LWV(wl10, Wl, 10) LWV(wl11, Wl, 11)
    LWV(wl12, Wl, 12) LWV(wl13, Wl, 13) LWV(wl14, Wl, 14) LWV(wl15, Wl, 15)
    LWV(wr0,  Wr, 0)  LWV(wr1,  Wr, 1)  LWV(wr2,  Wr, 2)  LWV(wr3,  Wr, 3)
    LWV(wr4,  Wr, 4)  LWV(wr5,  Wr, 5)  LWV(wr6,  Wr, 6)  LWV(wr7,  Wr, 7)
    LWV(wr8,  Wr, 8)  LWV(wr9,  Wr, 9)  LWV(wr10, Wr, 10) LWV(wr11, Wr, 11)
    LWV(wr12, Wr, 12) LWV(wr13, Wr, 13) LWV(wr14, Wr, 14) LWV(wr15, Wr, 15)
    const float bias = bl[lane];

    for (int r = wid; r < N; r += nw) {
        const long long base = (long long)r << 6;
        const float va = agg[base + lane];
        const float vx = xroot[base + lane];
        float acc0 = bias, acc1 = 0.f, acc2 = 0.f, acc3 = 0.f;
        TSTEP(0,  acc0) TSTEP(1,  acc1) TSTEP(2,  acc2) TSTEP(3,  acc3)
        TSTEP(4,  acc0) TSTEP(5,  acc1) TSTEP(6,  acc2) TSTEP(7,  acc3)
        TSTEP(8,  acc0) TSTEP(9,  acc1) TSTEP(10, acc2) TSTEP(11, acc3)
        TSTEP(12, acc0) TSTEP(13, acc1) TSTEP(14, acc2) TSTEP(15, acc3)
        const float acc = (acc0 + acc1) + (acc2 + acc3);
        out[base + lane] = fmaxf(acc, 0.0f);
    }
}

// ---------------------------------------------------------------------------
// Fallback (round-1) kernels, used only if ws_size is tiny.
// ---------------------------------------------------------------------------
__global__ void edge_scatter_kernel(
    const float* __restrict__ xu, const float* __restrict__ xr,
    const int* __restrict__ src, const int* __restrict__ dst,
    float* __restrict__ agg_r, float* __restrict__ agg_u,
    float* __restrict__ deg_r, float* __restrict__ deg_u,
    int nE)
{
    int tid  = blockIdx.x * blockDim.x + threadIdx.x;
    int e    = tid >> 4;
    if (e >= nE) return;
    int lane = tid & 15;
    int su = src[e];
    int dr = dst[e];
    if (lane == 0) {
        atomicAdd(&deg_r[dr], 1.0f);
        atomicAdd(&deg_u[su], 1.0f);
    }
    const float4 a = *reinterpret_cast<const float4*>(xu + ((long long)su << 6) + (lane << 2));
    const float4 b = *reinterpret_cast<const float4*>(xr + ((long long)dr << 6) + (lane << 2));
    float* pr = agg_r + ((long long)dr << 6) + (lane << 2);
    float* pu = agg_u + ((long long)su << 6) + (lane << 2);
    atomicAdd(pr + 0, a.x); atomicAdd(pr + 1, a.y);
    atomicAdd(pr + 2, a.z); atomicAdd(pr + 3, a.w);
    atomicAdd(pu + 0, b.x); atomicAdd(pu + 1, b.y);
    atomicAdd(pu + 2, b.z); atomicAdd(pu + 3, b.w);
}

__global__ void transform_kernel(
    const float* __restrict__ agg, const float* __restrict__ deg,
    const float* __restrict__ xroot,
    const float* __restrict__ Wl, const float* __restrict__ bl,
    const float* __restrict__ Wr,
    float* __restrict__ out, int N)
{
    __shared__ float sWl[64 * 64];
    __shared__ float sWr[64 * 64];
    __shared__ float sb[64];
    __shared__ float sAgg[4][64];
    __shared__ float sX[4][64];

    const int t = threadIdx.x;
    for (int i = t; i < 64 * 64; i += 256) {
        sWl[i] = Wl[i];
        sWr[i] = Wr[i];
    }
    if (t < 64) sb[t] = bl[t];
    __syncthreads();

    const int rg = t >> 6;
    const int h  = t & 63;

    for (long long r0 = (long long)blockIdx.x * 4; r0 < N; r0 += (long long)gridDim.x * 4) {
        const long long r = r0 + rg;
        if (r < N) {
            float inv = 1.0f / fmaxf(deg[r], 1.0f);
            sAgg[rg][h] = agg[(r << 6) + h] * inv;
            sX[rg][h]   = xroot[(r << 6) + h];
        }
        __syncthreads();
        if (r < N) {
            float acc = sb[h];
            #pragma unroll
            for (int d = 0; d < 64; ++d) {
                acc += sAgg[rg][d] * sWl[d * 64 + h] + sX[rg][d] * sWr[d * 64 + h];
            }
            out[(r << 6) + h] = fmaxf(acc, 0.0f);
        }
        __syncthreads();
    }
}

extern "C" void kernel_launch(void* const* d_in, const int* in_sizes, int n_in,
                              void* d_out, int out_size, void* d_ws, size_t ws_size,
                              hipStream_t stream)
{
    const float* xu    = (const float*)d_in[0];
    const float* xr    = (const float*)d_in[1];
    const int*   src   = (const int*)  d_in[2];
    const int*   dst   = (const int*)  d_in[3];
    const float* Wl_ur = (const float*)d_in[4];
    const float* bl_ur = (const float*)d_in[5];
    const float* Wr_ur = (const float*)d_in[6];
    const float* Wl_ru = (const float*)d_in[7];
    const float* bl_ru = (const float*)d_in[8];
    const float* Wr_ru = (const float*)d_in[9];

    const int Nu = in_sizes[0] / 64;
    const int Nr = in_sizes[1] / 64;
    const int nE = in_sizes[2];
    const int NN = Nr + Nu;

    float* out   = (float*)d_out;
    float* agg_r = out;                        // [Nr,64]
    float* agg_u = out + (long long)Nr * 64;   // [Nu,64]

    // ---- workspace layout ----
    int* cnt     = (int*)d_ws;                  // [NN]
    int* off     = cnt + NN;                    // [NN+1]
    int* partial = off + NN + 1;                // [256]
    int* nbr     = partial + 256;               // [2E]
    uintptr_t bfBase = ((uintptr_t)(nbr + 2ull * nE) + 15) & ~(uintptr_t)15;
    unsigned short* xub  = (unsigned short*)bfBase;         // [Nu*64]
    unsigned short* xrb  = xub + (size_t)Nu * 64;           // [Nr*64]
    unsigned short* aggb = xrb + (size_t)Nr * 64;           // [NN*64]
    unsigned short* Wt   = aggb + (size_t)NN * 64;          // [4*4096]
    const size_t needCsr  = ((size_t)NN + NN + 1 + 256 + 2ull * nE) * sizeof(int);
    const size_t needBf   = (bfBase - (uintptr_t)d_ws) + (size_t)NN * 64 * 2;
    const size_t needMfma = (bfBase - (uintptr_t)d_ws)
                          + ((size_t)NN * 64 + (size_t)NN * 64 + 4 * 4096) * 2;

    if (ws_size >= needCsr) {
        // ---------------- CSR path ----------------
        hipMemsetAsync(cnt, 0, (size_t)NN * sizeof(int), stream);

        const bool useBf   = (ws_size >= needBf);
        const bool useMfma = (ws_size >= needMfma);
        if (useBf) {
            const long long n4u = (long long)Nu * 16;
            const long long n4r = (long long)Nr * 16;
            tobf16_kernel<<<(int)((n4u + 255) / 256), 256, 0, stream>>>(xu, xub, n4u);
            tobf16_kernel<<<(int)((n4r + 255) / 256), 256, 0, stream>>>(xr, xrb, n4r);
        }
        if (useMfma) {
            wprep_kernel<<<64, 256, 0, stream>>>(Wl_ur, Wr_ur, Wl_ru, Wr_ru, Wt);
        }

        count_kernel<<<(nE + 255) / 256, 256, 0, stream>>>(src, dst, cnt, Nr, nE);

        const int nScanBlocks = (NN + SCAN_BS - 1) / SCAN_BS;   // <= 256
        scan_block_kernel<<<nScanBlocks, 256, 0, stream>>>(cnt, off, partial, NN);
        scan_partials_kernel<<<1, 256, 0, stream>>>(partial, nScanBlocks);
        scan_addback_kernel<<<(NN + 255) / 256, 256, 0, stream>>>(off, partial, NN, 2 * nE);

        const float invR = 8.0f / (float)Nr;
        const float invU = 8.0f / (float)Nu;
        const int PG = 2048;
        scatter_pers_kernel<<<PG, 256, 0, stream>>>(
            src, dst, off, cnt, nbr, Nr, nE, invR, invU, PG >> 3);

        const long long tg = (long long)NN * 16;
        const int gblocks = (int)((tg + 255) / 256);

        if (useMfma) {
            gather_bf16b_kernel<<<gblocks, 256, 0, stream>>>(
                xub, xrb, off, nbr, aggb, Nr, NN);
            const int tilesR = (Nr + 15) / 16;
            const int tilesU = (Nu + 15) / 16;
            transform_mfma_kernel<<<(tilesR + 3) / 4, 256, 0, stream>>>(
                aggb, xrb, Wt, Wt + 4096, bl_ur, agg_r, Nr);
            transform_mfma_kernel<<<(tilesU + 3) / 4, 256, 0, stream>>>(
                aggb + (size_t)Nr * 64, xub, Wt + 2 * 4096, Wt + 3 * 4096, bl_ru, agg_u, Nu);
        } else if (useBf) {
            gather_bf16_kernel<<<gblocks, 256, 0, stream>>>(
                xub, xrb, off, nbr, out, Nr, NN);
            transform_v4_kernel<<<1024, 256, 0, stream>>>(
                agg_r, xr, Wl_ur, bl_ur, Wr_ur, agg_r, Nr);
            transform_v4_kernel<<<1024, 256, 0, stream>>>(
                agg_u, xu, Wl_ru, bl_ru, Wr_ru, agg_u, Nu);
        } else {
            gather_mean_all_kernel<<<gblocks, 256, 0, stream>>>(
                xu, xr, off, nbr, out, Nr, NN);
            transform_v4_kernel<<<1024, 256, 0, stream>>>(
                agg_r, xr, Wl_ur, bl_ur, Wr_ur, agg_r, Nr);
            transform_v4_kernel<<<1024, 256, 0, stream>>>(
                agg_u, xu, Wl_ru, bl_ru, Wr_ru, agg_u, Nu);
        }
    } else {
        // ---------------- fallback: atomic path ----------------
        float* deg_r = (float*)d_ws;
        float* deg_u = deg_r + Nr;
        hipMemsetAsync(d_out, 0, (size_t)out_size * sizeof(float), stream);
        hipMemsetAsync(d_ws, 0, (size_t)NN * sizeof(float), stream);

        const long long total = (long long)nE * 16;
        edge_scatter_kernel<<<(int)((total + 255) / 256), 256, 0, stream>>>(
            xu, xr, src, dst, agg_r, agg_u, deg_r, deg_u, nE);

        transform_kernel<<<2048, 256, 0, stream>>>(
            agg_r, deg_r, xr, Wl_ur, bl_ur, Wr_ur, agg_r, Nr);
        transform_kernel<<<2048, 256, 0, stream>>>(
            agg_u, deg_u, xu, Wl_ru, bl_ru, Wr_ru, agg_u, Nu);
    }
}